// Round 4
// baseline (110.249 us; speedup 1.0000x reference)
//
#include <hip/hip_runtime.h>
#include <stdint.h>

// Log-sparse causal attention, B=4 L=2048 H=8 E=D=64, fp32 in/out.
// Allowed distances delta = q - j: {0..7, 9, 13, 21, 37, 69, 133, 261, 517, 1029}
//
// R8: stage K ONLY (near-K feeds the latency-critical score->softmax chain);
// V is read inline from global/L2 in the PV phase, whose 17 independent
// weighted-FMA groups hide load latency trivially. Staged footprint per block
// halves (84.5 -> 42.2 KB barrier-synced bytes), LDS 44.9 KB -> 2 blocks/CU
// resident (wave-limited, VGPR<=128): block n+1's staging overlaps block n's
// compute. R7 was 1 block/CU -> phase-serialized CU (stage, barrier, compute
// with idle HBM pipe) and measured == R6 despite fewer instructions; the
// critical path, not instruction count, is the limiter.
// 4 lanes/query x 16 dims/lane; shfl_xor 1,2 only (quad-perm DPP).
// Row padded to 68 floats (272 B): bank start (4*row+16*sub) mod 32 -> even
// spread, minimal 8-cycle ds_read_b128 (PADF=64 would be 16-way conflicted).

static constexpr int Bn = 4, Ln = 2048, Hn = 8, En = 64;
static constexpr int QPB = 128;           // queries per block
static constexpr int NT  = 512;           // threads per block (8 waves)
static constexpr int NEAR_MAX = 37;       // deltas <= this: K staged in LDS
static constexpr int SPAN = NEAR_MAX + QPB;   // 165 rows: q0-37 .. q0+127
static constexpr int PADF = 68;           // floats per LDS row
static constexpr int NNEAR = 12;
static constexpr int NFAR  = 5;
static constexpr int NDELTA = NNEAR + NFAR;

__global__ __launch_bounds__(NT) void logsparse_attn_kernel(
    const float* __restrict__ Q,
    const float* __restrict__ K,
    const float* __restrict__ V,
    float* __restrict__ O)
{
    constexpr int nearD[NNEAR] = {0,1,2,3,4,5,6,7,9,13,21,37};
    constexpr int farD[NFAR]   = {69,133,261,517,1029};

    __shared__ float Ks[SPAN * PADF];     // 44.9 KB: K rows only

    // 512 blocks = 32 (b,h) x 16 query-chunks; bh = blockIdx%32 keeps each
    // bh's 16 blocks on XCD (bh%8) under round-robin dispatch.
    const int bh = blockIdx.x & 31;
    const int l  = blockIdx.x >> 5;
    const int b  = bh >> 3;
    const int h  = bh & 7;
    const int q0 = l * QPB;

    const int tid = threadIdx.x;
    const size_t bhBase = ((size_t)b * Ln * Hn + (size_t)h) * (size_t)En;
    constexpr int ROWF = Hn * En;         // 512 floats between consecutive rows

    const int sub = tid & 3;              // 4 lanes per query, 16 dims each
    const int qq  = tid >> 2;             // query within block [0,128)
    const int q   = q0 + qq;
    const int dimOff = sub * 16;
    const size_t rowQ = bhBase + (size_t)q * ROWF + dimOff;

    // ---- issue Q loads first (independent of staging) ----
    const float4 q0v = *(const float4*)(Q + rowQ);
    const float4 q1v = *(const float4*)(Q + rowQ + 4);
    const float4 q2v = *(const float4*)(Q + rowQ + 8);
    const float4 q3v = *(const float4*)(Q + rowQ + 12);

    // ---- cooperative staging: 165 K-rows x 16 float4-chunks ----
    for (int idx = tid; idx < SPAN * 16; idx += NT) {
        const int rid = idx >> 4;
        const int ch  = idx & 15;
        int g = q0 - NEAR_MAX + rid;
        if (g < 0) g = 0;                 // finite data; masked later via p=0
        *(float4*)(Ks + rid * PADF + ch * 4) =
            *(const float4*)(K + bhBase + (size_t)g * ROWF + ch * 4);
    }

    // ---- Q chunk (16 floats), fold scale = 1/sqrt(64) ----
    const float qf[16] = {
        q0v.x*0.125f, q0v.y*0.125f, q0v.z*0.125f, q0v.w*0.125f,
        q1v.x*0.125f, q1v.y*0.125f, q1v.z*0.125f, q1v.w*0.125f,
        q2v.x*0.125f, q2v.y*0.125f, q2v.z*0.125f, q2v.w*0.125f,
        q3v.x*0.125f, q3v.y*0.125f, q3v.z*0.125f, q3v.w*0.125f };

    __syncthreads();

    // ---- scores: 12 near (LDS) + 5 far (global, inline loads) ----
    float sc[NDELTA];
    #pragma unroll
    for (int d = 0; d < NNEAR; ++d) {
        const int del = nearD[d];
        const float* kp = Ks + (qq + NEAR_MAX - del) * PADF + dimOff;
        const float4 k0 = *(const float4*)(kp);
        const float4 k1 = *(const float4*)(kp + 4);
        const float4 k2 = *(const float4*)(kp + 8);
        const float4 k3 = *(const float4*)(kp + 12);
        float s = qf[0]*k0.x + qf[1]*k0.y + qf[2]*k0.z  + qf[3]*k0.w
                + qf[4]*k1.x + qf[5]*k1.y + qf[6]*k1.z  + qf[7]*k1.w
                + qf[8]*k2.x + qf[9]*k2.y + qf[10]*k2.z + qf[11]*k2.w
                + qf[12]*k3.x+ qf[13]*k3.y+ qf[14]*k3.z + qf[15]*k3.w;
        s += __shfl_xor(s, 1);            // quad-perm DPP
        s += __shfl_xor(s, 2);            // quad-perm DPP
        sc[d] = (q - del < 0) ? -__builtin_inff() : s;
    }
    #pragma unroll
    for (int d = 0; d < NFAR; ++d) {
        const int del = farD[d];
        float s = -__builtin_inff();
        if (q0 + QPB - 1 >= del) {        // block-uniform: skip dead deltas
            const int j  = q - del;
            const int jc = (j < 0) ? 0 : j;   // p==0 later when j<0
            const float* kp = K + bhBase + (size_t)jc * ROWF + dimOff;
            const float4 k0 = *(const float4*)(kp);
            const float4 k1 = *(const float4*)(kp + 4);
            const float4 k2 = *(const float4*)(kp + 8);
            const float4 k3 = *(const float4*)(kp + 12);
            float t = qf[0]*k0.x + qf[1]*k0.y + qf[2]*k0.z  + qf[3]*k0.w
                    + qf[4]*k1.x + qf[5]*k1.y + qf[6]*k1.z  + qf[7]*k1.w
                    + qf[8]*k2.x + qf[9]*k2.y + qf[10]*k2.z + qf[11]*k2.w
                    + qf[12]*k3.x+ qf[13]*k3.y+ qf[14]*k3.z + qf[15]*k3.w;
            t += __shfl_xor(t, 1);
            t += __shfl_xor(t, 2);
            s = (j < 0) ? -__builtin_inff() : t;
        }
        sc[NNEAR + d] = s;
    }

    // ---- softmax over 17 scores; p overwrites sc (register economy) ----
    float m = sc[0];
    #pragma unroll
    for (int d = 1; d < NDELTA; ++d) m = fmaxf(m, sc[d]);
    float sum = 0.0f;
    #pragma unroll
    for (int d = 0; d < NDELTA; ++d) {
        sc[d] = __expf(sc[d] - m);        // exp(-inf)=0 for masked
        sum += sc[d];
    }
    const float inv = 1.0f / sum;

    // ---- weighted sum of V rows: ALL from global (L2-resident rows).
    // 17 independent load->FMA groups; latency hidden by unrolled issue. ----
    float acc[16] = {0,0,0,0,0,0,0,0,0,0,0,0,0,0,0,0};
    #pragma unroll
    for (int d = 0; d < NDELTA; ++d) {
        const int del = (d < NNEAR) ? nearD[d] : farD[d - NNEAR];
        if (d < NNEAR || q0 + QPB - 1 >= del) {   // uniform skip for far
            const int j  = q - del;
            const int jc = (j < 0) ? 0 : j;       // p==0 covers j<0
            const float* vp = V + bhBase + (size_t)jc * ROWF + dimOff;
            const float4 v0 = *(const float4*)(vp);
            const float4 v1 = *(const float4*)(vp + 4);
            const float4 v2 = *(const float4*)(vp + 8);
            const float4 v3 = *(const float4*)(vp + 12);
            const float w = sc[d];
            acc[0]  = fmaf(w, v0.x, acc[0]);
            acc[1]  = fmaf(w, v0.y, acc[1]);
            acc[2]  = fmaf(w, v0.z, acc[2]);
            acc[3]  = fmaf(w, v0.w, acc[3]);
            acc[4]  = fmaf(w, v1.x, acc[4]);
            acc[5]  = fmaf(w, v1.y, acc[5]);
            acc[6]  = fmaf(w, v1.z, acc[6]);
            acc[7]  = fmaf(w, v1.w, acc[7]);
            acc[8]  = fmaf(w, v2.x, acc[8]);
            acc[9]  = fmaf(w, v2.y, acc[9]);
            acc[10] = fmaf(w, v2.z, acc[10]);
            acc[11] = fmaf(w, v2.w, acc[11]);
            acc[12] = fmaf(w, v3.x, acc[12]);
            acc[13] = fmaf(w, v3.y, acc[13]);
            acc[14] = fmaf(w, v3.z, acc[14]);
            acc[15] = fmaf(w, v3.w, acc[15]);
        }
    }

    float4 o0, o1, o2, o3;
    o0.x = acc[0]*inv;  o0.y = acc[1]*inv;  o0.z = acc[2]*inv;  o0.w = acc[3]*inv;
    o1.x = acc[4]*inv;  o1.y = acc[5]*inv;  o1.z = acc[6]*inv;  o1.w = acc[7]*inv;
    o2.x = acc[8]*inv;  o2.y = acc[9]*inv;  o2.z = acc[10]*inv; o2.w = acc[11]*inv;
    o3.x = acc[12]*inv; o3.y = acc[13]*inv; o3.z = acc[14]*inv; o3.w = acc[15]*inv;
    *(float4*)(O + rowQ)      = o0;
    *(float4*)(O + rowQ + 4)  = o1;
    *(float4*)(O + rowQ + 8)  = o2;
    *(float4*)(O + rowQ + 12) = o3;
}

extern "C" void kernel_launch(void* const* d_in, const int* in_sizes, int n_in,
                              void* d_out, int out_size, void* d_ws, size_t ws_size,
                              hipStream_t stream) {
    const float* Q = (const float*)d_in[0];
    const float* K = (const float*)d_in[1];
    const float* V = (const float*)d_in[2];
    float* O = (float*)d_out;

    const int nblocks = Bn * Hn * (Ln / QPB);   // 512 blocks, 128 queries each
    logsparse_attn_kernel<<<nblocks, NT, 0, stream>>>(Q, K, V, O);
}

// Round 5
// 104.000 us; speedup vs baseline: 1.0601x; 1.0601x over previous
//
#include <hip/hip_runtime.h>
#include <stdint.h>

// Log-sparse causal attention, B=4 L=2048 H=8 E=D=64, fp32 in/out.
// Allowed distances delta = q - j: {0..7, 9, 13, 21, 37, 69, 133, 261, 517, 1029}
//
// R9: software-pipelined persistent blocks. R8's counters showed pure latency
// serialization (VALU 10%, HBM 12%, Occ 31%): the stage->__syncthreads->compute
// structure exposes staging latency every block, and __syncthreads drains vmcnt.
// Now: 512 blocks (exactly 2/CU, co-resident), each owns 4 chunks of 32
// queries; K+V double-buffered in LDS (2 x 37.5 KB = 75 KB). Staging loads for
// chunk c+1 are issued at the END of chunk c-1 and fly across the whole compute
// of chunk c (T14 async-STAGE split); ds_write + lgkmcnt(0) + RAW s_barrier
// (keeps vmcnt un-drained across the barrier, unlike __syncthreads). One
// barrier/chunk; buf[x]'s previous reader (chunk c-1) and writer (end of c)
// are separated by the end-of-(c-1) barrier -> race-free.
// 8 lanes/query x 8 dims; reduce = shfl_xor 1,2,4. V stays in LDS (R8 lesson:
// inline global V collapsed ILP). Far deltas {69..1029} inline from L2 with
// chunk-uniform dead-delta skip. PADF=68 spreads b128 reads over banks.

static constexpr int Bn = 4, Ln = 2048, Hn = 8, En = 64;
static constexpr int QPC = 32;            // queries per chunk
static constexpr int NCHUNK = 4;          // chunks per block (128 queries)
static constexpr int NT  = 256;           // threads per block (4 waves)
static constexpr int NEAR_MAX = 37;       // deltas <= this: staged in LDS
static constexpr int SPAN = NEAR_MAX + QPC;   // 69 rows per chunk
static constexpr int PADF = 68;           // floats per LDS row
static constexpr int KSLOT = SPAN * 16;   // float4 slots per array (1104)
static constexpr int SLOTS = KSLOT * 2;   // K + V slots (2208)
static constexpr int PERT  = (SLOTS + NT - 1) / NT;  // 9 float4 per thread
static constexpr int NNEAR = 12;
static constexpr int NFAR  = 5;
static constexpr int ND    = NNEAR + NFAR;

__global__ __launch_bounds__(NT) void logsparse_attn_kernel(
    const float* __restrict__ Q,
    const float* __restrict__ K,
    const float* __restrict__ V,
    float* __restrict__ O)
{
    constexpr int nearD[NNEAR] = {0,1,2,3,4,5,6,7,9,13,21,37};
    constexpr int farD[NFAR]   = {69,133,261,517,1029};

    __shared__ float Ks[2][SPAN * PADF];
    __shared__ float Vs[2][SPAN * PADF];

    // 512 blocks = 32 (b,h) x 16 groups of 128 consecutive queries.
    // bh = blockIdx%32 keeps (b,h) L2-local per XCD under round-robin.
    const int bh  = blockIdx.x & 31;
    const int grp = blockIdx.x >> 5;
    const int b   = bh >> 3;
    const int h   = bh & 7;
    const int qbase = grp * (QPC * NCHUNK);

    const int tid = threadIdx.x;
    const size_t bhBase = ((size_t)b * Ln * Hn + (size_t)h) * (size_t)En;
    constexpr int ROWF = Hn * En;         // 512 floats between rows

    const int sub = tid & 7;              // 8 lanes/query, 8 dims each
    const int qq  = tid >> 3;             // query within chunk [0,32)
    const int dimOff = sub * 8;

    // ---- staging registers (9 float4/thread) + issue/write helpers ----
    float4 st0, st1, st2, st3, st4, st5, st6, st7, st8;
    float4* stp[PERT] = { &st0,&st1,&st2,&st3,&st4,&st5,&st6,&st7,&st8 };

    auto issueStage = [&](int qc0) {
        #pragma unroll
        for (int i = 0; i < PERT; ++i) {
            int idx = tid + i * NT;
            if (idx > SLOTS - 1) idx = SLOTS - 1;   // dup writes: same data
            const int kvi = idx >= KSLOT;
            const int rem = idx - kvi * KSLOT;
            const int ridi = rem >> 4, chi = rem & 15;
            int g = qc0 - NEAR_MAX + ridi;
            if (g < 0) g = 0;                       // masked later via p=0
            const float* src = (kvi ? V : K) + bhBase + (size_t)g * ROWF + chi * 4;
            *stp[i] = *(const float4*)src;
        }
    };
    auto writeStage = [&](int bi) {
        #pragma unroll
        for (int i = 0; i < PERT; ++i) {
            int idx = tid + i * NT;
            if (idx > SLOTS - 1) idx = SLOTS - 1;
            const int kvi = idx >= KSLOT;
            const int rem = idx - kvi * KSLOT;
            const int ridi = rem >> 4, chi = rem & 15;
            float* dst = (kvi ? &Vs[bi][0] : &Ks[bi][0]) + ridi * PADF + chi * 4;
            *(float4*)dst = *stp[i];
        }
    };

    float4 qn0, qn1;                      // next-chunk Q, kept in flight
    auto issueQ = [&](int qc0) {
        const size_t rq = bhBase + (size_t)(qc0 + qq) * ROWF + dimOff;
        qn0 = *(const float4*)(Q + rq);
        qn1 = *(const float4*)(Q + rq + 4);
    };

    // ---- prologue: stage chunk0 -> buf0; leave chunk1 loads in flight ----
    issueStage(qbase);                    // chunk 0
    writeStage(0);                        // compiler inserts counted vmcnt
    issueQ(qbase);                        // Q(chunk0), in flight
    issueStage(qbase + QPC);              // chunk 1, in flight across barrier
    asm volatile("s_waitcnt lgkmcnt(0)" ::: "memory");
    __builtin_amdgcn_sched_barrier(0);
    __builtin_amdgcn_s_barrier();
    __builtin_amdgcn_sched_barrier(0);

    // ---- 4-chunk pipelined loop (fully unrolled: static buf indices) ----
    #pragma unroll
    for (int c = 0; c < NCHUNK; ++c) {
        const int qc0 = qbase + QPC * c;
        const int q   = qc0 + qq;
        const int bi  = c & 1;
        const size_t rowQ = bhBase + (size_t)q * ROWF + dimOff;

        // qf from prefetched Q (fold scale 1/8); then refill qn for c+1
        const float qf[8] = { qn0.x*0.125f, qn0.y*0.125f, qn0.z*0.125f, qn0.w*0.125f,
                              qn1.x*0.125f, qn1.y*0.125f, qn1.z*0.125f, qn1.w*0.125f };
        if (c + 1 < NCHUNK) issueQ(qc0 + QPC);

        // ---- scores: 12 near (LDS) + 5 far (global/L2 inline) ----
        float sc[ND];
        #pragma unroll
        for (int d = 0; d < NNEAR; ++d) {
            const int del = nearD[d];
            const float* kp = &Ks[bi][(qq + NEAR_MAX - del) * PADF + dimOff];
            const float4 k0 = *(const float4*)kp;
            const float4 k1 = *(const float4*)(kp + 4);
            float s = qf[0]*k0.x + qf[1]*k0.y + qf[2]*k0.z + qf[3]*k0.w
                    + qf[4]*k1.x + qf[5]*k1.y + qf[6]*k1.z + qf[7]*k1.w;
            s += __shfl_xor(s, 1);
            s += __shfl_xor(s, 2);
            s += __shfl_xor(s, 4);
            sc[d] = (q - del < 0) ? -__builtin_inff() : s;
        }
        #pragma unroll
        for (int d = 0; d < NFAR; ++d) {
            const int del = farD[d];
            float s = -__builtin_inff();
            if (qc0 + QPC - 1 >= del) {   // chunk-uniform dead-delta skip
                const int j  = q - del;
                const int jc = (j < 0) ? 0 : j;
                const float* kp = K + bhBase + (size_t)jc * ROWF + dimOff;
                const float4 k0 = *(const float4*)kp;
                const float4 k1 = *(const float4*)(kp + 4);
                float t = qf[0]*k0.x + qf[1]*k0.y + qf[2]*k0.z + qf[3]*k0.w
                        + qf[4]*k1.x + qf[5]*k1.y + qf[6]*k1.z + qf[7]*k1.w;
                t += __shfl_xor(t, 1);
                t += __shfl_xor(t, 2);
                t += __shfl_xor(t, 4);
                s = (j < 0) ? -__builtin_inff() : t;
            }
            sc[NNEAR + d] = s;
        }

        // ---- softmax over 17 scores (delta=0 valid -> finite max) ----
        float m = sc[0];
        #pragma unroll
        for (int d = 1; d < ND; ++d) m = fmaxf(m, sc[d]);
        float sum = 0.0f;
        #pragma unroll
        for (int d = 0; d < ND; ++d) {
            sc[d] = __expf(sc[d] - m);    // exp(-inf)=0 for masked
            sum += sc[d];
        }
        const float inv = 1.0f / sum;

        // ---- PV: near from LDS, far inline ----
        float acc[8] = {0,0,0,0,0,0,0,0};
        #pragma unroll
        for (int d = 0; d < NNEAR; ++d) {
            const int del = nearD[d];
            const float* vp = &Vs[bi][(qq + NEAR_MAX - del) * PADF + dimOff];
            const float4 v0 = *(const float4*)vp;
            const float4 v1 = *(const float4*)(vp + 4);
            const float w = sc[d];
            acc[0] = fmaf(w, v0.x, acc[0]);
            acc[1] = fmaf(w, v0.y, acc[1]);
            acc[2] = fmaf(w, v0.z, acc[2]);
            acc[3] = fmaf(w, v0.w, acc[3]);
            acc[4] = fmaf(w, v1.x, acc[4]);
            acc[5] = fmaf(w, v1.y, acc[5]);
            acc[6] = fmaf(w, v1.z, acc[6]);
            acc[7] = fmaf(w, v1.w, acc[7]);
        }
        #pragma unroll
        for (int d = 0; d < NFAR; ++d) {
            const int del = farD[d];
            if (qc0 + QPC - 1 >= del) {   // uniform; p==0 covers j<0
                const int j  = q - del;
                const int jc = (j < 0) ? 0 : j;
                const float* vp = V + bhBase + (size_t)jc * ROWF + dimOff;
                const float4 v0 = *(const float4*)vp;
                const float4 v1 = *(const float4*)(vp + 4);
                const float w = sc[NNEAR + d];
                acc[0] = fmaf(w, v0.x, acc[0]);
                acc[1] = fmaf(w, v0.y, acc[1]);
                acc[2] = fmaf(w, v0.z, acc[2]);
                acc[3] = fmaf(w, v0.w, acc[3]);
                acc[4] = fmaf(w, v1.x, acc[4]);
                acc[5] = fmaf(w, v1.y, acc[5]);
                acc[6] = fmaf(w, v1.z, acc[6]);
                acc[7] = fmaf(w, v1.w, acc[7]);
            }
        }

        float4 o0, o1;
        o0.x = acc[0]*inv; o0.y = acc[1]*inv; o0.z = acc[2]*inv; o0.w = acc[3]*inv;
        o1.x = acc[4]*inv; o1.y = acc[5]*inv; o1.z = acc[6]*inv; o1.w = acc[7]*inv;
        *(float4*)(O + rowQ)     = o0;
        *(float4*)(O + rowQ + 4) = o1;

        // ---- pipeline tail: publish chunk c+1, launch chunk c+2 ----
        if (c + 1 < NCHUNK) {
            writeStage((c + 1) & 1);      // vmcnt counted by compiler; loads
                                          // were issued one full chunk ago
            if (c + 2 < NCHUNK) issueStage(qc0 + 2 * QPC);
            asm volatile("s_waitcnt lgkmcnt(0)" ::: "memory");
            __builtin_amdgcn_sched_barrier(0);
            __builtin_amdgcn_s_barrier();  // raw: vmcnt NOT drained
            __builtin_amdgcn_sched_barrier(0);
        }
    }
}

extern "C" void kernel_launch(void* const* d_in, const int* in_sizes, int n_in,
                              void* d_out, int out_size, void* d_ws, size_t ws_size,
                              hipStream_t stream) {
    const float* Q = (const float*)d_in[0];
    const float* K = (const float*)d_in[1];
    const float* V = (const float*)d_in[2];
    float* O = (float*)d_out;

    const int nblocks = Bn * Hn * (Ln / (QPC * NCHUNK));   // 512 blocks
    logsparse_attn_kernel<<<nblocks, NT, 0, stream>>>(Q, K, V, O);
}

// Round 6
// 100.290 us; speedup vs baseline: 1.0993x; 1.0370x over previous
//
#include <hip/hip_runtime.h>
#include <stdint.h>

// Log-sparse causal attention, B=4 L=2048 H=8 E=D=64, fp32 in/out.
// Allowed distances delta = q - j: {0..7, 9, 13, 21, 37, 69, 133, 261, 517, 1029}
//
// R10 = R6 (best config: QPB=64/NT=512, K+V staged, NEAR_MAX=37, 2 blocks/CU
// = 16 waves/CU) + R5's epoch-merging prefetches, WITHOUT R5's fatal
// __launch_bounds__(512,4) VGPR cap (that forced VGPR=64 -> 40 floats/thread
// scratch spill). Rationale: R4/R6/R7/R9 all land ~33-37us with <15% on every
// pipe -> the limiter is serial dependent latency epochs per wave
// (stage->barrier; far-K->score; far-V->PV), not throughput or occupancy.
//  - far-K loads issue BEFORE __syncthreads: its vmcnt(0) drain (needed for
//    staging anyway) completes them for free -> far-K epoch vanishes.
//  - far-V loads issue right after far-K consumption, BEFORE softmax: their
//    latency hides under softmax VALU + near-PV LDS reads.
//  - fk registers die before fv registers are born -> allocator reuse, peak
//    VGPR ~110 < 128 (4 waves/SIMD preserved). Guard: WRITE_SIZE must stay
//    ~16.4 MB (output only). R5 lesson: spill shows as WRITE_SIZE 4x.
// 8 lanes/query x 8 dims; reduce = shfl_xor 1,2,4. PADF=68 (272 B rows)
// spreads ds_read_b128 bank starts (4r+8s mod 32) -> max 2-way (free).

static constexpr int Bn = 4, Ln = 2048, Hn = 8, En = 64;
static constexpr int QPB = 64;            // queries per block
static constexpr int NT  = 512;           // threads per block (8 waves)
static constexpr int NEAR_MAX = 37;       // deltas <= this: staged in LDS
static constexpr int SPAN = NEAR_MAX + QPB;   // 101 rows: q0-37 .. q0+63
static constexpr int PADF = 68;           // floats per LDS row
static constexpr int NNEAR = 12;
static constexpr int NFAR  = 5;
static constexpr int ND    = NNEAR + NFAR;

__global__ __launch_bounds__(NT) void logsparse_attn_kernel(
    const float* __restrict__ Q,
    const float* __restrict__ K,
    const float* __restrict__ V,
    float* __restrict__ O)
{
    constexpr int nearD[NNEAR] = {0,1,2,3,4,5,6,7,9,13,21,37};
    constexpr int farD[NFAR]   = {69,133,261,517,1029};

    __shared__ float Ks[SPAN * PADF];
    __shared__ float Vs[SPAN * PADF];

    // 1024 blocks = 32 (b,h) x 32 query-chunks; bh = blockIdx%32 keeps each
    // (b,h) on one XCD under round-robin dispatch (K+V slice ~2MB -> L2).
    const int bh = blockIdx.x & 31;
    const int l  = blockIdx.x >> 5;
    const int b  = bh >> 3;
    const int h  = bh & 7;
    const int q0 = l * QPB;

    const int tid = threadIdx.x;
    const size_t bhBase = ((size_t)b * Ln * Hn + (size_t)h) * (size_t)En;
    constexpr int ROWF = Hn * En;         // 512 floats between rows

    const int sub = tid & 7;              // 8 lanes/query, 8 dims each
    const int qq  = tid >> 3;             // query within block [0,64)
    const int q   = q0 + qq;
    const int dimOff = sub * 8;
    const size_t rowQ = bhBase + (size_t)q * ROWF + dimOff;

    // ---- Q load first (in flight across staging) ----
    const float4 q0v = *(const float4*)(Q + rowQ);
    const float4 q1v = *(const float4*)(Q + rowQ + 4);

    // ---- cooperative staging: 101 rows x 16 float4-chunks, K and V fused ----
    for (int idx = tid; idx < SPAN * 16; idx += NT) {
        const int rid = idx >> 4;
        const int ch  = idx & 15;
        int g = q0 - NEAR_MAX + rid;
        if (g < 0) g = 0;                 // finite data; masked later via p=0
        const size_t srcOff = bhBase + (size_t)g * ROWF + ch * 4;
        const int dst = rid * PADF + ch * 4;
        *(float4*)(Ks + dst) = *(const float4*)(K + srcOff);
        *(float4*)(Vs + dst) = *(const float4*)(V + srcOff);
    }

    // ---- far-K prefetch BEFORE the barrier: __syncthreads drains vmcnt
    // anyway for the staging stores, so these complete for free. ----
    const bool farOn = true;              // per-delta guards below (uniform)
    float4 fk0_0, fk0_1, fk1_0, fk1_1, fk2_0, fk2_1, fk3_0, fk3_1, fk4_0, fk4_1;
    {
        #define LOAD_FK(i)                                                     \
        {                                                                      \
            const int del = farD[i];                                           \
            if (q0 + QPB - 1 >= del) {                                         \
                const int j  = q - del;                                        \
                const int jc = (j < 0) ? 0 : j;                                \
                const float* kp = K + bhBase + (size_t)jc * ROWF + dimOff;     \
                fk##i##_0 = *(const float4*)kp;                                \
                fk##i##_1 = *(const float4*)(kp + 4);                          \
            }                                                                  \
        }
        LOAD_FK(0) LOAD_FK(1) LOAD_FK(2) LOAD_FK(3) LOAD_FK(4)
        #undef LOAD_FK
    }
    (void)farOn;

    // ---- Q chunk (8 floats), fold scale = 1/sqrt(64) ----
    const float qf[8] = { q0v.x*0.125f, q0v.y*0.125f, q0v.z*0.125f, q0v.w*0.125f,
                          q1v.x*0.125f, q1v.y*0.125f, q1v.z*0.125f, q1v.w*0.125f };

    __syncthreads();

    // ---- near scores from LDS (12 deltas) ----
    float sc[ND];
    #pragma unroll
    for (int d = 0; d < NNEAR; ++d) {
        const int del = nearD[d];
        const float* kp = Ks + (qq + NEAR_MAX - del) * PADF + dimOff;
        const float4 k0 = *(const float4*)kp;
        const float4 k1 = *(const float4*)(kp + 4);
        float s = qf[0]*k0.x + qf[1]*k0.y + qf[2]*k0.z + qf[3]*k0.w
                + qf[4]*k1.x + qf[5]*k1.y + qf[6]*k1.z + qf[7]*k1.w;
        s += __shfl_xor(s, 1);
        s += __shfl_xor(s, 2);
        s += __shfl_xor(s, 4);
        sc[d] = (q - del < 0) ? -__builtin_inff() : s;
    }

    // ---- far scores from prefetched registers (already resident) ----
    {
        #define FAR_SCORE(i)                                                   \
        {                                                                      \
            const int del = farD[i];                                           \
            float s = -__builtin_inff();                                       \
            if (q0 + QPB - 1 >= del) {                                         \
                float t = qf[0]*fk##i##_0.x + qf[1]*fk##i##_0.y                \
                        + qf[2]*fk##i##_0.z + qf[3]*fk##i##_0.w                \
                        + qf[4]*fk##i##_1.x + qf[5]*fk##i##_1.y                \
                        + qf[6]*fk##i##_1.z + qf[7]*fk##i##_1.w;               \
                t += __shfl_xor(t, 1);                                         \
                t += __shfl_xor(t, 2);                                         \
                t += __shfl_xor(t, 4);                                         \
                s = (q - del < 0) ? -__builtin_inff() : t;                     \
            }                                                                  \
            sc[NNEAR + i] = s;                                                 \
        }
        FAR_SCORE(0) FAR_SCORE(1) FAR_SCORE(2) FAR_SCORE(3) FAR_SCORE(4)
        #undef FAR_SCORE
    }

    // ---- far-V prefetch: issues now, lands during softmax + near-PV.
    // fk registers are dead here -> allocator reuses them for fv. ----
    float4 fv0_0, fv0_1, fv1_0, fv1_1, fv2_0, fv2_1, fv3_0, fv3_1, fv4_0, fv4_1;
    {
        #define LOAD_FV(i)                                                     \
        {                                                                      \
            const int del = farD[i];                                           \
            if (q0 + QPB - 1 >= del) {                                         \
                const int j  = q - del;                                        \
                const int jc = (j < 0) ? 0 : j;                                \
                const float* vp = V + bhBase + (size_t)jc * ROWF + dimOff;     \
                fv##i##_0 = *(const float4*)vp;                                \
                fv##i##_1 = *(const float4*)(vp + 4);                          \
            }                                                                  \
        }
        LOAD_FV(0) LOAD_FV(1) LOAD_FV(2) LOAD_FV(3) LOAD_FV(4)
        #undef LOAD_FV
    }

    // ---- softmax over 17 scores (delta=0 valid -> finite max) ----
    float m = sc[0];
    #pragma unroll
    for (int d = 1; d < ND; ++d) m = fmaxf(m, sc[d]);
    float sum = 0.0f;
    #pragma unroll
    for (int d = 0; d < ND; ++d) {
        sc[d] = __expf(sc[d] - m);        // exp(-inf)=0 for masked
        sum += sc[d];
    }
    const float inv = 1.0f / sum;

    // ---- PV: near from LDS (far-V latency hides under this) ----
    float acc[8] = {0,0,0,0,0,0,0,0};
    #pragma unroll
    for (int d = 0; d < NNEAR; ++d) {
        const int del = nearD[d];
        const float* vp = Vs + (qq + NEAR_MAX - del) * PADF + dimOff;
        const float4 v0 = *(const float4*)vp;
        const float4 v1 = *(const float4*)(vp + 4);
        const float w = sc[d];
        acc[0] = fmaf(w, v0.x, acc[0]);
        acc[1] = fmaf(w, v0.y, acc[1]);
        acc[2] = fmaf(w, v0.z, acc[2]);
        acc[3] = fmaf(w, v0.w, acc[3]);
        acc[4] = fmaf(w, v1.x, acc[4]);
        acc[5] = fmaf(w, v1.y, acc[5]);
        acc[6] = fmaf(w, v1.z, acc[6]);
        acc[7] = fmaf(w, v1.w, acc[7]);
    }

    // ---- far PV from prefetched registers ----
    {
        #define FAR_PV(i)                                                      \
        {                                                                      \
            const int del = farD[i];                                           \
            if (q0 + QPB - 1 >= del) {    /* uniform; p==0 covers j<0 */       \
                const float w = sc[NNEAR + i];                                 \
                acc[0] = fmaf(w, fv##i##_0.x, acc[0]);                         \
                acc[1] = fmaf(w, fv##i##_0.y, acc[1]);                         \
                acc[2] = fmaf(w, fv##i##_0.z, acc[2]);                         \
                acc[3] = fmaf(w, fv##i##_0.w, acc[3]);                         \
                acc[4] = fmaf(w, fv##i##_1.x, acc[4]);                         \
                acc[5] = fmaf(w, fv##i##_1.y, acc[5]);                         \
                acc[6] = fmaf(w, fv##i##_1.z, acc[6]);                         \
                acc[7] = fmaf(w, fv##i##_1.w, acc[7]);                         \
            }                                                                  \
        }
        FAR_PV(0) FAR_PV(1) FAR_PV(2) FAR_PV(3) FAR_PV(4)
        #undef FAR_PV
    }

    float4 o0, o1;
    o0.x = acc[0]*inv; o0.y = acc[1]*inv; o0.z = acc[2]*inv; o0.w = acc[3]*inv;
    o1.x = acc[4]*inv; o1.y = acc[5]*inv; o1.z = acc[6]*inv; o1.w = acc[7]*inv;
    *(float4*)(O + rowQ)     = o0;
    *(float4*)(O + rowQ + 4) = o1;
}

extern "C" void kernel_launch(void* const* d_in, const int* in_sizes, int n_in,
                              void* d_out, int out_size, void* d_ws, size_t ws_size,
                              hipStream_t stream) {
    const float* Q = (const float*)d_in[0];
    const float* K = (const float*)d_in[1];
    const float* V = (const float*)d_in[2];
    float* O = (float*)d_out;

    const int nblocks = Bn * Hn * (Ln / QPB);   // 1024 blocks, 64 queries each
    logsparse_attn_kernel<<<nblocks, NT, 0, stream>>>(Q, K, V, O);
}